// Round 2
// baseline (99.833 us; speedup 1.0000x reference)
//
#include <hip/hip_runtime.h>

// CombinedLoss: 0.99 * dice + 0.01 * mean(phi * sigmoid(pred))
// phi = signed exact EDT of targets mask (16 x 512 x 512), |phi|>1e5 -> 0.
//
// Round 5: capped bit-mask EDT with HALO=8 + single-kernel finalize.
// Exactness argument for the tighter cap: the column lower-envelope result is
// accepted only when m2 <= 81 = (HALO+1)^2. Any candidate g^2+k^2 <= 81 needs
// g <= 9 (stored exactly: the 64-bit window reaches >= 24 bits each side) and
// k <= 8 (scanned). A true nearer site at k = 9 has d^2 >= 81 and can only tie;
// k >= 10 gives >= 100. Capped (g>=10 -> <=63) and OOR-sentinel entries only
// produce candidates > 81, so they can never fake an accepted value. Anything
// unresolved (> 81) takes the exact global fallback (probability ~2^-254 per
// pixel on Bernoulli(0.5) data), so the kernel is exact for ANY input.
// Phase-1 rows per block drop 48 -> 32, k-loop cap 16 -> 8.
//
// finalize is folded in via last-block reduction: ws counter (offset 16 KB)
// zeroed by a 4-byte hipMemsetAsync each call, device-scope atomicAdd +
// __threadfence ordering on the 512x4 double partials.
//
// ws: double partials[512][4] at offset 0; unsigned int counter at 16384.

#define HH 512
#define WW 512
#define BH 16      // output rows per block
#define HALO 8
#define TR 32      // LDS tile rows = BH + 2*HALO
#define NT 512     // threads per block
#define NBLK 512   // 16 images * 32 slabs
#define NGRP 4     // BH*WW / (NT*4)
#define T2MAX 81   // (HALO+1)^2 acceptance threshold

// exact per-pixel fallback: full-image search with pruning (ultra-rare path)
__device__ float fallback_exact(const int* __restrict__ t, int n, int y, int x,
                                bool fg, float m2) {
    const int* tn = t + (n << 18);
    for (int yy = 0; yy < HH; ++yy) {
        float dy = (float)(yy - y);
        float dy2 = dy * dy;
        if (dy2 >= m2) continue;
        const int* row = tn + (yy << 9);
        int lim = (int)sqrtf(m2 - dy2);
        if (lim > WW) lim = WW;
        for (int dx = 0; dx <= lim; ++dx) {
            bool hit = false;
            int xl = x - dx, xr = x + dx;
            if (xl >= 0) { int v = row[xl]; hit = fg ? (v == 0) : (v != 0); }
            if (!hit && xr < WW) { int v = row[xr]; hit = fg ? (v == 0) : (v != 0); }
            if (hit) {
                float c = fmaf((float)dx, (float)dx, dy2);
                if (c < m2) m2 = c;
                break;
            }
        }
    }
    return m2;
}

__global__ __launch_bounds__(NT, 4) void edt_fused(const int* __restrict__ t,
                                                   const float* __restrict__ pred,
                                                   double* __restrict__ partials,
                                                   unsigned int* __restrict__ count,
                                                   float* __restrict__ out) {
    __shared__ unsigned long long msk[TR][8];   // 2 KB: fg-site bit per pixel
    __shared__ unsigned char gb[TR][WW];        // 16 KB: class(2b) | capped g(6b)
    __shared__ double sred[8][4];
    __shared__ int lastblk;

    const int n     = blockIdx.x >> 5;
    const int y0    = (blockIdx.x & 31) << 4;
    const int rbase = y0 - HALO;
    const int wave  = threadIdx.x >> 6;   // 0..7
    const int lane  = threadIdx.x & 63;
    const int x0    = lane << 3;

    // ---------------- phase 1a: build per-row 512-bit site masks ----------------
    for (int rr = wave; rr < TR; rr += 8) {
        const int gy = rbase + rr;
        if (gy < 0 || gy >= HH) continue;   // OOR rows handled in 1b
        const int4* tp = (const int4*)(t + (n << 18) + (gy << 9) + x0);
        int4 ta = tp[0], tb = tp[1];
        unsigned int byte = 0;
        byte |= (unsigned int)(ta.x != 0) << 0;
        byte |= (unsigned int)(ta.y != 0) << 1;
        byte |= (unsigned int)(ta.z != 0) << 2;
        byte |= (unsigned int)(ta.w != 0) << 3;
        byte |= (unsigned int)(tb.x != 0) << 4;
        byte |= (unsigned int)(tb.y != 0) << 5;
        byte |= (unsigned int)(tb.z != 0) << 6;
        byte |= (unsigned int)(tb.w != 0) << 7;
        ((unsigned char*)&msk[rr][0])[lane] = (unsigned char)byte;
    }
    __syncthreads();

    // ---------------- phase 1b: capped 1D row distances -> bytes ----------------
    // lane covers pixels [x0, x0+7]; window = mask bits [x0-24, x0+39] (reach
    // >= 24 left / >= 32 right around every covered pixel — ample for cap 9).
    // Bits outside [0,512) masked invalid for BOTH classes via V.
    {
        const int s  = (lane - 3) << 3;      // window start bit (may be <0)
        const int sh = s & 63;
        const int j0 = s >> 6;               // arithmetic shift: -24>>6 = -1
        unsigned long long V = ~0ull;
        if (s < 0)   V &= (~0ull) << (-s);
        if (s > 448) V &= (~0ull) >> (s - 448);   // s+64 > 512

        for (int rr = wave; rr < TR; rr += 8) {
            const int gy = rbase + rr;
            unsigned long long pk;
            if (gy < 0 || gy >= HH) {
                pk = 0xBFBFBFBFBFBFBFBFull;   // class=2 (OOR), g=63: far for both fields
            } else {
                unsigned long long w0 = (j0 >= 0) ? msk[rr][j0] : 0ull;
                unsigned long long w1 = (j0 < 7) ? msk[rr][j0 + 1] : 0ull;
                unsigned long long win = sh ? ((w0 >> sh) | (w1 << (64 - sh))) : w0;
                pk = 0ull;
#pragma unroll
                for (int i = 0; i < 8; ++i) {
                    const int c = 24 + i;                       // center bit of pixel i
                    unsigned int b = (unsigned int)(win >> c) & 1u;  // own class
                    unsigned long long mm = (b ? ~win : win) & V;    // opposite-class sites
                    unsigned long long lo = mm & ((1ull << c) - 1ull);
                    unsigned long long hi = mm >> (c + 1);
                    int dl = lo ? (c - 63 + __builtin_clzll(lo)) : 64;
                    int dr = hi ? (1 + (int)__builtin_ctzll(hi)) : 64;
                    int g = min(min(dl, dr), 63);               // >9 == "far" for acceptance
                    pk |= ((unsigned long long)((b << 6) | (unsigned int)g)) << (i * 8);
                }
            }
            *((unsigned long long*)&gb[rr][x0]) = pk;
        }
    }
    __syncthreads();

    // ---------------- phase 2: integer column envelope + fused loss ----------------
    double s_b = 0.0, s_p = 0.0, s_i = 0.0;
    int s_t = 0;

#pragma unroll 1
    for (int grp = 0; grp < NGRP; ++grp) {
        const int pid = (grp * NT + threadIdx.x) << 2;   // 4 consecutive px
        const int yl  = pid >> 9;                        // 0..15
        const int x   = pid & 511;
        const int r   = yl + HALO;                       // 8..23 -> r+-8 in [0,31]

        const float4 p4 = *((const float4*)(pred + (n << 18) + ((y0 + yl) << 9) + x));
        const float pv[4] = {p4.x, p4.y, p4.z, p4.w};

        const unsigned int ow = *((const unsigned int*)&gb[r][x]);
        int  m2[4], wc[4];
        bool fg[4];
        int  mx = 0;
#pragma unroll
        for (int j = 0; j < 4; ++j) {
            unsigned int bj  = (ow >> (8 * j)) & 255u;
            unsigned int cls = bj >> 6;
            int gg = (int)(bj & 63u);
            fg[j] = (cls == 1u);
            wc[j] = fg[j] ? 0 : 1;     // class code whose presence means distance 0
            m2[j] = gg * gg;
            mx = max(mx, m2[j]);
        }

        for (int k = 1; k <= HALO; ++k) {
            const int k2 = k * k;
            if (k2 >= mx) break;
            const unsigned int bd = *((const unsigned int*)&gb[r - k][x]);
            const unsigned int bu = *((const unsigned int*)&gb[r + k][x]);
            mx = 0;
#pragma unroll
            for (int j = 0; j < 4; ++j) {
                if (k2 < m2[j]) {
                    unsigned int dj = (bd >> (8 * j)) & 255u;
                    unsigned int uj = (bu >> (8 * j)) & 255u;
                    int a = ((int)(dj >> 6) == wc[j]) ? 0 : (int)(dj & 63u);
                    int b = ((int)(uj >> 6) == wc[j]) ? 0 : (int)(uj & 63u);
                    m2[j] = min(m2[j], min(a * a + k2, b * b + k2));
                }
                mx = max(mx, m2[j]);
            }
        }

        float df[4];
#pragma unroll
        for (int j = 0; j < 4; ++j) df[j] = sqrtf((float)m2[j]);

        if (mx > T2MAX) {   // some pixel unresolved past cap/halo (never on random data)
#pragma unroll
            for (int j = 0; j < 4; ++j)
                if (m2[j] > T2MAX) {
                    // pass huge bound: capped m2 is sentinel-inflated, not a true bound
                    float fm2 = fallback_exact(t, n, y0 + yl, x + j, fg[j], 1.0e12f);
                    df[j] = sqrtf(fm2);
                }
        }

#pragma unroll
        for (int j = 0; j < 4; ++j) {
            float p = 1.0f / (1.0f + expf(-pv[j]));
            float phi = fg[j] ? -df[j] : df[j];
            if (df[j] > 1.0e4f) phi = 0.0f;   // "no sites" case only; matches |phi|>1e5 -> 0
            s_b += (double)(phi * p);
            s_p += (double)p;
            if (fg[j]) { s_i += (double)p; s_t += 1; }
        }
    }
    double s_tt = (double)s_t;

    // ---------------- block reduce -> partials row ----------------
#pragma unroll
    for (int off = 32; off > 0; off >>= 1) {
        s_b  += __shfl_xor(s_b,  off, 64);
        s_p  += __shfl_xor(s_p,  off, 64);
        s_i  += __shfl_xor(s_i,  off, 64);
        s_tt += __shfl_xor(s_tt, off, 64);
    }
    if (lane == 0) {
        sred[wave][0] = s_b; sred[wave][1] = s_p; sred[wave][2] = s_i; sred[wave][3] = s_tt;
    }
    __syncthreads();
    if (threadIdx.x == 0) {
        double* dst = partials + (size_t)blockIdx.x * 4;
#pragma unroll
        for (int c = 0; c < 4; ++c) {
            double acc = 0.0;
#pragma unroll
            for (int wv = 0; wv < 8; ++wv) acc += sred[wv][c];
            dst[c] = acc;
        }
        __threadfence();                                  // release partials
        unsigned int prev = atomicAdd(count, 1u);         // device-scope
        lastblk = (prev == NBLK - 1u) ? 1 : 0;
    }
    __syncthreads();

    // ---------------- last block: fold 512 partial rows -> loss scalar ----------------
    if (lastblk) {
        __threadfence();                                  // acquire partials
        const double* src = partials + (size_t)threadIdx.x * 4;
        double r0 = src[0], r1 = src[1], r2 = src[2], r3 = src[3];
#pragma unroll
        for (int off = 32; off > 0; off >>= 1) {
            r0 += __shfl_xor(r0, off, 64);
            r1 += __shfl_xor(r1, off, 64);
            r2 += __shfl_xor(r2, off, 64);
            r3 += __shfl_xor(r3, off, 64);
        }
        if (lane == 0) { sred[wave][0] = r0; sred[wave][1] = r1; sred[wave][2] = r2; sred[wave][3] = r3; }
        __syncthreads();
        if (threadIdx.x == 0) {
            double sb = 0.0, sp = 0.0, si = 0.0, st = 0.0;
#pragma unroll
            for (int wv = 0; wv < 8; ++wv) {
                sb += sred[wv][0]; sp += sred[wv][1]; si += sred[wv][2]; st += sred[wv][3];
            }
            double dice = 1.0 - (2.0 * si + 1e-6) / (sp + st + 1e-6);
            double boundary = sb / (double)(16 * 512 * 512);
            out[0] = (float)(0.99 * dice + 0.01 * boundary);
        }
    }
}

extern "C" void kernel_launch(void* const* d_in, const int* in_sizes, int n_in,
                              void* d_out, int out_size, void* d_ws, size_t ws_size,
                              hipStream_t stream) {
    const float* pred = (const float*)d_in[0];
    const int*   targ = (const int*)d_in[1];
    double* partials = (double*)d_ws;                          // 512 * 4 doubles
    unsigned int* count = (unsigned int*)((char*)d_ws + 16384);
    float* out = (float*)d_out;

    hipMemsetAsync(count, 0, sizeof(unsigned int), stream);    // graph-capture-safe
    edt_fused<<<NBLK, NT, 0, stream>>>(targ, pred, partials, count, out);
}

// Round 3
// 93.512 us; speedup vs baseline: 1.0676x; 1.0676x over previous
//
#include <hip/hip_runtime.h>

// CombinedLoss: 0.99 * dice + 0.01 * mean(phi * sigmoid(pred))
// phi = signed exact EDT of targets mask (16 x 512 x 512), |phi|>1e5 -> 0.
//
// Round 6: REVERT to the measured-best round-3 kernel (94.27 us this session).
// Rounds 4-5 (capped bit-mask EDT, HALO=8, fused finalize) both regressed
// (+3.7, +1.9 us): the per-iteration time is dominated by two harness-owned
// 256 MB workspace poison fills (~88 us at 75-77% HBM peak, stream-ordered
// before our kernels); the controllable slice is ~6 us vs a ~5.1 us floor for
// reading targets+preds once. This kernel sits on that floor; the rewrites
// only added halo fetch redundancy and dispatch/fence overhead.
//
// Structure: single fused EDT kernel. Each block owns a 32-row slab of one
// image and computes the 1D row-distance fields for slab+16-row halo into
// LDS (u32 = g0 | g1<<16 per pixel, 64x512x4 = 128 KB), then runs the
// column lower-envelope scan + loss sums entirely from LDS. A pixel whose
// distance isn't resolved within the halo (needs k>16, never happens on
// Bernoulli(0.5) data) takes an exact global-t fallback, so the kernel is
// exact for ANY input.
//
// ws: double partials[256][4] at offset 0 (fully rewritten every call).

#define HH 512
#define WW 512
#define BH 32      // output rows per block
#define HALO 16
#define TR 64      // LDS tile rows
#define NT 512     // threads per block
#define NBLK 256   // 16 images * 16 slabs
#define SENT 65535.0f

// exact per-pixel fallback: full-image search with pruning (ultra-rare path)
__device__ float fallback_exact(const int* __restrict__ t, int n, int y, int x,
                                bool fg, float m2) {
    const int* tn = t + (n << 18);
    for (int yy = 0; yy < HH; ++yy) {
        float dy = (float)(yy - y);
        float dy2 = dy * dy;
        if (dy2 >= m2) continue;
        const int* row = tn + (yy << 9);
        int lim = (int)sqrtf(m2 - dy2);
        for (int dx = 0; dx <= lim; ++dx) {
            bool hit = false;
            int xl = x - dx, xr = x + dx;
            if (xl >= 0) { int v = row[xl]; hit = fg ? (v == 0) : (v != 0); }
            if (!hit && xr < WW) { int v = row[xr]; hit = fg ? (v == 0) : (v != 0); }
            if (hit) {
                float c = fmaf((float)dx, (float)dx, dy2);
                if (c < m2) m2 = c;
                break;
            }
        }
    }
    return m2;
}

__global__ __launch_bounds__(NT, 1) void edt_fused(const int* __restrict__ t,
                                                   const float* __restrict__ pred,
                                                   double* __restrict__ partials) {
    __shared__ unsigned int gl[TR][WW];   // 128 KB: lo16 = g0 (sites=bg), hi16 = g1 (sites=fg)
    __shared__ double sred[8][4];

    const int n     = blockIdx.x >> 4;
    const int y0    = (blockIdx.x & 15) << 5;
    const int rbase = y0 - HALO;
    const int wave  = threadIdx.x >> 6;   // 0..7
    const int lane  = threadIdx.x & 63;
    const int x0    = lane << 3;
    const float BIG = 3.0e37f;

    // ---------------- phase 1: 1D row scans (both fields) into LDS ----------------
    for (int rr = wave; rr < TR; rr += 8) {
        const int gy = rbase + rr;
        if (gy < 0 || gy >= HH) {
            uint4 s = {0xFFFFFFFFu, 0xFFFFFFFFu, 0xFFFFFFFFu, 0xFFFFFFFFu};
            *((uint4*)&gl[rr][x0])     = s;
            *((uint4*)&gl[rr][x0 + 4]) = s;
            continue;
        }
        const int4* tp = (const int4*)(t + (n << 18) + (gy << 9) + x0);
        int4 ta = tp[0], tb = tp[1];
        int tv[8] = {ta.x, ta.y, ta.z, ta.w, tb.x, tb.y, tb.z, tb.w};

        float pen[2][8];
#pragma unroll
        for (int i = 0; i < 8; ++i) {
            bool fg = (tv[i] != 0);
            pen[0][i] = fg ? 1.0e6f : 0.0f;   // sites = background
            pen[1][i] = fg ? 0.0f : 1.0e6f;   // sites = foreground
        }

        unsigned short gout[2][8];
#pragma unroll
        for (int f = 0; f < 2; ++f) {
            float pf[8];
            float run = BIG;
#pragma unroll
            for (int i = 0; i < 8; ++i) { run = fminf(run, pen[f][i] - (float)(x0 + i)); pf[i] = run; }
            float incl = run;
#pragma unroll
            for (int off = 1; off < 64; off <<= 1) {
                float u = __shfl_up(incl, (unsigned)off, 64);
                if (lane >= off) incl = fminf(incl, u);
            }
            float excl = __shfl_up(incl, 1u, 64);
            if (lane == 0) excl = BIG;

            float sf[8];
            run = BIG;
#pragma unroll
            for (int i = 7; i >= 0; --i) { run = fminf(run, pen[f][i] + (float)(x0 + i)); sf[i] = run; }
            float inclb = run;
#pragma unroll
            for (int off = 1; off < 64; off <<= 1) {
                float u = __shfl_down(inclb, (unsigned)off, 64);
                if (lane + off < 64) inclb = fminf(inclb, u);
            }
            float exclb = __shfl_down(inclb, 1u, 64);
            if (lane == 63) exclb = BIG;

#pragma unroll
            for (int i = 0; i < 8; ++i) {
                float xa = (float)(x0 + i);
                float fa = xa + fminf(pf[i], excl);
                float ba = -xa + fminf(sf[i], exclb);
                gout[f][i] = (unsigned short)fminf(fminf(fa, ba), SENT);
            }
        }

        unsigned int pk[8];
#pragma unroll
        for (int i = 0; i < 8; ++i)
            pk[i] = (unsigned int)gout[0][i] | ((unsigned int)gout[1][i] << 16);
        uint4 o0 = {pk[0], pk[1], pk[2], pk[3]};
        uint4 o1 = {pk[4], pk[5], pk[6], pk[7]};
        *((uint4*)&gl[rr][x0])     = o0;
        *((uint4*)&gl[rr][x0 + 4]) = o1;
    }
    __syncthreads();

    // ---------------- phase 2: column scan + fused loss sums ----------------
    double s_b = 0.0, s_p = 0.0, s_i = 0.0;
    int s_t = 0;

#pragma unroll 1
    for (int grp = 0; grp < 8; ++grp) {
        const int pid = (grp * NT + threadIdx.x) << 2;   // 0..16383, 4 consecutive px
        const int yl  = pid >> 9;                        // 0..31
        const int x   = pid & 511;
        const int r   = yl + HALO;                       // 16..47 -> r-16 >= 0, r+16 <= 63

        const float4 p4 = *((const float4*)(pred + (n << 18) + ((y0 + yl) << 9) + x));
        const float pv[4] = {p4.x, p4.y, p4.z, p4.w};

        const uint4 ow = *((const uint4*)&gl[r][x]);
        const unsigned int w[4] = {ow.x, ow.y, ow.z, ow.w};

        bool  fg[4];
        float m2[4];
        float mx = 0.0f;
#pragma unroll
        for (int j = 0; j < 4; ++j) {
            unsigned int lo = w[j] & 0xFFFFu, hi = w[j] >> 16;
            fg[j] = (hi == 0u);
            float gv = (float)(fg[j] ? lo : hi);
            m2[j] = gv * gv;
            mx = fmaxf(mx, m2[j]);
        }

        for (int k = 1; k <= HALO; ++k) {
            float k2 = (float)(k * k);
            if (k2 >= mx) break;
            const uint4 wd4 = *((const uint4*)&gl[r - k][x]);
            const uint4 wu4 = *((const uint4*)&gl[r + k][x]);
            const unsigned int wd[4] = {wd4.x, wd4.y, wd4.z, wd4.w};
            const unsigned int wu[4] = {wu4.x, wu4.y, wu4.z, wu4.w};
            mx = 0.0f;
#pragma unroll
            for (int j = 0; j < 4; ++j) {
                if (k2 < m2[j]) {
                    unsigned int a = fg[j] ? (wd[j] & 0xFFFFu) : (wd[j] >> 16);
                    unsigned int b = fg[j] ? (wu[j] & 0xFFFFu) : (wu[j] >> 16);
                    float fa = (float)a, fb = (float)b;
                    m2[j] = fminf(m2[j], fminf(fmaf(fa, fa, k2), fmaf(fb, fb, k2)));
                }
                mx = fmaxf(mx, m2[j]);
            }
        }

        if (mx > 289.0f) {   // some pixel unresolved past halo (never on random data)
#pragma unroll
            for (int j = 0; j < 4; ++j)
                if (m2[j] > 289.0f)
                    m2[j] = fallback_exact(t, n, y0 + yl, x + j, fg[j], m2[j]);
        }

#pragma unroll
        for (int j = 0; j < 4; ++j) {
            float p = 1.0f / (1.0f + expf(-pv[j]));
            float d = sqrtf(m2[j]);
            float phi = fg[j] ? -d : d;
            if (d > 1.0e4f) phi = 0.0f;   // sentinel-derived only; matches |phi|>1e5 -> 0
            s_b += (double)(phi * p);
            s_p += (double)p;
            if (fg[j]) { s_i += (double)p; s_t += 1; }
        }
    }
    double s_tt = (double)s_t;

    // ---------------- block reduce ----------------
#pragma unroll
    for (int off = 32; off > 0; off >>= 1) {
        s_b  += __shfl_xor(s_b,  off, 64);
        s_p  += __shfl_xor(s_p,  off, 64);
        s_i  += __shfl_xor(s_i,  off, 64);
        s_tt += __shfl_xor(s_tt, off, 64);
    }
    if (lane == 0) {
        sred[wave][0] = s_b; sred[wave][1] = s_p; sred[wave][2] = s_i; sred[wave][3] = s_tt;
    }
    __syncthreads();
    if (threadIdx.x == 0) {
        double* dst = partials + (size_t)blockIdx.x * 4;
#pragma unroll
        for (int c = 0; c < 4; ++c) {
            double acc = 0.0;
#pragma unroll
            for (int wv = 0; wv < 8; ++wv) acc += sred[wv][c];
            dst[c] = acc;
        }
    }
}

// ---------------- finalize: 256 partial rows -> loss scalar ----------------
__global__ __launch_bounds__(256) void finalize_loss(const double* __restrict__ partials,
                                                     float* __restrict__ out) {
    const int wave = threadIdx.x >> 6;
    const int lane = threadIdx.x & 63;
    const double* src = partials + (size_t)threadIdx.x * 4;
    double s0 = src[0], s1 = src[1], s2 = src[2], s3 = src[3];
#pragma unroll
    for (int off = 32; off > 0; off >>= 1) {
        s0 += __shfl_xor(s0, off, 64);
        s1 += __shfl_xor(s1, off, 64);
        s2 += __shfl_xor(s2, off, 64);
        s3 += __shfl_xor(s3, off, 64);
    }
    __shared__ double red[4][4];
    if (lane == 0) { red[wave][0] = s0; red[wave][1] = s1; red[wave][2] = s2; red[wave][3] = s3; }
    __syncthreads();
    if (threadIdx.x == 0) {
        double sb = red[0][0] + red[1][0] + red[2][0] + red[3][0];
        double sp = red[0][1] + red[1][1] + red[2][1] + red[3][1];
        double si = red[0][2] + red[1][2] + red[2][2] + red[3][2];
        double st = red[0][3] + red[1][3] + red[2][3] + red[3][3];
        double dice = 1.0 - (2.0 * si + 1e-6) / (sp + st + 1e-6);
        double boundary = sb / (double)(16 * 512 * 512);
        out[0] = (float)(0.99 * dice + 0.01 * boundary);
    }
}

extern "C" void kernel_launch(void* const* d_in, const int* in_sizes, int n_in,
                              void* d_out, int out_size, void* d_ws, size_t ws_size,
                              hipStream_t stream) {
    const float* pred = (const float*)d_in[0];
    const int*   targ = (const int*)d_in[1];
    double* partials = (double*)d_ws;        // 256 * 4 doubles, fully rewritten
    float* out = (float*)d_out;

    edt_fused<<<NBLK, NT, 0, stream>>>(targ, pred, partials);
    finalize_loss<<<1, 256, 0, stream>>>(partials, out);
}